// Round 11
// baseline (1227.758 us; speedup 1.0000x reference)
//
#include <hip/hip_runtime.h>

#define ZD 256    // Z_NH
#define NE 1000   // NUM_ENTRY
#define NP 1024   // padded entries

typedef __attribute__((ext_vector_type(8))) short short8;
typedef __attribute__((ext_vector_type(4))) float f32x4;

static __device__ __forceinline__ unsigned short f2bf(float x) {
    unsigned u = __float_as_uint(x);
    u = (u + 0x7FFFu + ((u >> 16) & 1u)) >> 16;
    return (unsigned short)u;
}
static __device__ __forceinline__ float bf2f(unsigned short u) {
    return __uint_as_float((unsigned)u << 16);
}

// ---------------------------------------------------------------------------
// prep_e: eh (bf16 swizzled, in ws) + el (bf16 swizzled residual, stored in
// out_q rows 0..1023 bytes +512..+1023) + en exact pairwise.
// ---------------------------------------------------------------------------
__global__ __launch_bounds__(64) void prep_e(const float* __restrict__ emb,
                                             unsigned char* __restrict__ ebB,
                                             float* __restrict__ en,
                                             float* __restrict__ out) {
    int e = blockIdx.x * 64 + threadIdx.x;
    if (e >= NP) return;
    unsigned base = (unsigned)e * 512u;
    unsigned x = ((unsigned)e & 7u) << 4;
    unsigned char* elB = (unsigned char*)out + (size_t)e * 1024u + 512u;
    if (e < NE) {
        const float* row = emb + (size_t)e * ZD;
        for (int k = 0; k < ZD; k += 2) {  // 2k%4==0, pair stays in same dword
            unsigned off  = (base + 2u * k) ^ x;
            unsigned off2 = (2u * (unsigned)k) ^ x;
            unsigned short h0 = f2bf(row[k]);
            unsigned short h1 = f2bf(row[k + 1]);
            *(unsigned short*)(ebB + off)     = h0;
            *(unsigned short*)(ebB + off + 2) = h1;
            *(unsigned short*)(elB + off2)     = f2bf(__fsub_rn(row[k],     bf2f(h0)));
            *(unsigned short*)(elB + off2 + 2) = f2bf(__fsub_rn(row[k + 1], bf2f(h1)));
        }
        float r[8];
        #pragma unroll
        for (int j = 0; j < 8; ++j) { float v = row[j]; r[j] = __fmul_rn(v, v); }
        for (int i = 8; i < 128; i += 8)
            #pragma unroll
            for (int j = 0; j < 8; ++j) { float v = row[i + j]; r[j] = __fadd_rn(r[j], __fmul_rn(v, v)); }
        float s1 = __fadd_rn(__fadd_rn(__fadd_rn(r[0], r[1]), __fadd_rn(r[2], r[3])),
                             __fadd_rn(__fadd_rn(r[4], r[5]), __fadd_rn(r[6], r[7])));
        #pragma unroll
        for (int j = 0; j < 8; ++j) { float v = row[128 + j]; r[j] = __fmul_rn(v, v); }
        for (int i = 136; i < 256; i += 8)
            #pragma unroll
            for (int j = 0; j < 8; ++j) { float v = row[i + j]; r[j] = __fadd_rn(r[j], __fmul_rn(v, v)); }
        float s2 = __fadd_rn(__fadd_rn(__fadd_rn(r[0], r[1]), __fadd_rn(r[2], r[3])),
                             __fadd_rn(__fadd_rn(r[4], r[5]), __fadd_rn(r[6], r[7])));
        en[e] = __fadd_rn(s1, s2);
    } else {
        for (int k = 0; k < 128; ++k) {
            *(unsigned*)(ebB + base + 4u * k) = 0u;
            *(unsigned*)(elB + 4u * k) = 0u;
        }
        en[e] = __builtin_inff();
    }
}

// ---------------------------------------------------------------------------
// prep_h: hn only (exact numpy-pairwise, stored in out_i region as float bits)
// ---------------------------------------------------------------------------
__global__ __launch_bounds__(256) void prep_h(const float* __restrict__ h,
                                              float* __restrict__ hn) {
    __shared__ float L[64][257];
    const int t = threadIdx.x;
    const long row0 = (long)blockIdx.x * 64;
    const int kq = (t & 63) * 4;
    const int rq = t >> 6;
    #pragma unroll
    for (int p = 0; p < 16; ++p) {
        int row = p * 4 + rq;
        float4 v = *(const float4*)(h + (row0 + row) * ZD + kq);
        L[row][kq] = v.x; L[row][kq + 1] = v.y; L[row][kq + 2] = v.z; L[row][kq + 3] = v.w;
    }
    __syncthreads();
    if (t < 64) {
        float r[8];
        #pragma unroll
        for (int j = 0; j < 8; ++j) { float v = L[t][j]; r[j] = __fmul_rn(v, v); }
        for (int i = 8; i < 128; i += 8)
            #pragma unroll
            for (int j = 0; j < 8; ++j) { float v = L[t][i + j]; r[j] = __fadd_rn(r[j], __fmul_rn(v, v)); }
        float s1 = __fadd_rn(__fadd_rn(__fadd_rn(r[0], r[1]), __fadd_rn(r[2], r[3])),
                             __fadd_rn(__fadd_rn(r[4], r[5]), __fadd_rn(r[6], r[7])));
        #pragma unroll
        for (int j = 0; j < 8; ++j) { float v = L[t][128 + j]; r[j] = __fmul_rn(v, v); }
        for (int i = 136; i < 256; i += 8)
            #pragma unroll
            for (int j = 0; j < 8; ++j) { float v = L[t][i + j]; r[j] = __fadd_rn(r[j], __fmul_rn(v, v)); }
        float s2 = __fadd_rn(__fadd_rn(__fadd_rn(r[0], r[1]), __fadd_rn(r[2], r[3])),
                             __fadd_rn(__fadd_rn(r[4], r[5]), __fadd_rn(r[6], r[7])));
        hn[row0 + t] = __fadd_rn(s1, s2);
    }
}

// ---------------------------------------------------------------------------
// K1 main: split-precision bf16 MFMA (hh*eh + hh*el + hl*eh) -> approx error
// ~2e-5 -> tau shrinks 7x -> verify set ~2% of rows. 128-entry chunks x 8
// (eh 64KB + el 64KB LDS). A-frags built from f32 h on the fly.
// Epilogue: cnt==1 rows resolved here (out_l[r]=besti); others get record
// (+0..7), worklist entry (+8 of row rbase0+pos), count (+10 of rbase0).
// ---------------------------------------------------------------------------
__global__ __launch_bounds__(1024, 4) void vq_main(const float* __restrict__ h,
                                                   const float* __restrict__ emb,
                                                   const unsigned char* __restrict__ ebB,
                                                   const float* __restrict__ en,
                                                   float* out, int M) {
    extern __shared__ char lds[];
    char* BsEH = lds;                         // 65536 B eh chunk (swizzled)
    char* BsEL = lds + 65536;                 // 65536 B el chunk (swizzled)
    float* en_s = (float*)(lds + 131072);     // 128 floats
    int* blkcnt = (int*)(lds + 131072 + 512);

    const int t  = threadIdx.x;
    const int lane = t & 63;
    const int wv = t >> 6;                    // 0..15
    const int g  = lane >> 4;                 // 0..3
    const int lg = lane & 15;
    const long rbase = (long)blockIdx.x * 256 + wv * 16;
    const long rbase0 = (long)blockIdx.x * 256;

    const float* hnp = out + (size_t)M * ZD;  // hn values (out_i region)

    if (t == 0) *blkcnt = 0;

    // ---- A fragments from f32 h: row rbase+lg, k = kt*32 + g*8 .. +8 ----
    short8 hhf[8], hlf[8];
    {
        const float* hr = h + (size_t)(rbase + lg) * ZD;
        #pragma unroll
        for (int kt = 0; kt < 8; ++kt) {
            float4 v0 = *(const float4*)(hr + kt * 32 + g * 8);
            float4 v1 = *(const float4*)(hr + kt * 32 + g * 8 + 4);
            float vv[8] = {v0.x, v0.y, v0.z, v0.w, v1.x, v1.y, v1.z, v1.w};
            short8 hh, hl;
            #pragma unroll
            for (int j = 0; j < 8; ++j) {
                unsigned short b = f2bf(vv[j]);
                hh[j] = (short)b;
                hl[j] = (short)f2bf(__fsub_rn(vv[j], bf2f(b)));
            }
            hhf[kt] = hh; hlf[kt] = hl;
        }
    }
    float hnr[4], taur[4];
    #pragma unroll
    for (int i = 0; i < 4; ++i) {
        hnr[i] = hnp[rbase + g * 4 + i];
        // split-precision bound: |d_approx-d_exact| <= ~7.7e-5 worst-case;
        // tau >= 2*Delta with ~3x margin.
        taur[i] = 1.0e-6f * sqrtf(256.0f * hnr[i]) + 2.5e-4f;
    }

    const float INF = __builtin_inff();
    float bv0[4], bv1[4], bv2[4], bv3[4];
    int   bi0[4], bi1[4], bi2[4], bi3[4];
    #pragma unroll
    for (int i = 0; i < 4; ++i) {
        bv0[i] = INF; bv1[i] = INF; bv2[i] = INF; bv3[i] = INF;
        bi0[i] = 0;   bi1[i] = 0;   bi2[i] = 0;   bi3[i] = 0;
    }

    for (int c = 0; c < 8; ++c) {
        { // stage eh (ws) and el (out_q rows, bytes +512..1023) linearly
            const uint4* srcEH = (const uint4*)(ebB + (size_t)c * 65536);
            uint4* dstEH = (uint4*)BsEH;
            #pragma unroll
            for (int p = 0; p < 4; ++p) dstEH[p * 1024 + t] = srcEH[p * 1024 + t];
            #pragma unroll
            for (int p = 0; p < 4; ++p) {
                int idx = p * 1024 + t;       // 0..4095
                int row = idx >> 5;           // 0..127
                int sub = idx & 31;           // uint4 within 512B
                uint4 v = *(const uint4*)((const char*)out +
                            (size_t)(c * 128 + row) * 1024 + 512 + sub * 16);
                *(uint4*)(BsEL + row * 512 + sub * 16) = v;
            }
        }
        if (t < 32) {
            float4 v = *(const float4*)(en + c * 128 + t * 4);
            *(float4*)(en_s + t * 4) = v;
        }
        __syncthreads();

        for (int nt = 0; nt < 8; ++nt) {
            f32x4 a0 = {0.f, 0.f, 0.f, 0.f};   // hh*eh
            f32x4 a1 = {0.f, 0.f, 0.f, 0.f};   // hh*el
            f32x4 a2 = {0.f, 0.f, 0.f, 0.f};   // hl*eh
            const int nb = nt * 16 + lg;        // entry in chunk 0..127
            const unsigned x = ((unsigned)lg & 7u) << 4;
            const unsigned rowb = (unsigned)nb * 512u;
            #pragma unroll
            for (int kt = 0; kt < 8; ++kt) {
                const unsigned off = (rowb + (unsigned)kt * 64u + g * 16u) ^ x;
                short8 beh = *(const short8*)(BsEH + off);
                short8 bel = *(const short8*)(BsEL + off);
                a0 = __builtin_amdgcn_mfma_f32_16x16x32_bf16(hhf[kt], beh, a0, 0, 0, 0);
                a1 = __builtin_amdgcn_mfma_f32_16x16x32_bf16(hhf[kt], bel, a1, 0, 0, 0);
                a2 = __builtin_amdgcn_mfma_f32_16x16x32_bf16(hlf[kt], beh, a2, 0, 0, 0);
            }
            const int eIdx = c * 128 + nb;
            const float ene = en_s[nb];
            #pragma unroll
            for (int i = 0; i < 4; ++i) {
                float dot = __fadd_rn(__fadd_rn(a0[i], a1[i]), a2[i]);
                float d = __fsub_rn(__fadd_rn(hnr[i], ene), __fmul_rn(2.0f, dot));
                if (__any(d < bv3[i])) {
                    bool l3 = d < bv3[i], l2 = d < bv2[i], l1 = d < bv1[i], l0 = d < bv0[i];
                    bv3[i] = l3 ? (l2 ? bv2[i] : d) : bv3[i];
                    bi3[i] = l3 ? (l2 ? bi2[i] : eIdx) : bi3[i];
                    bv2[i] = l2 ? (l1 ? bv1[i] : d) : bv2[i];
                    bi2[i] = l2 ? (l1 ? bi1[i] : eIdx) : bi2[i];
                    bv1[i] = l1 ? (l0 ? bv0[i] : d) : bv1[i];
                    bi1[i] = l1 ? (l0 ? bi0[i] : eIdx) : bi1[i];
                    bv0[i] = l0 ? d : bv0[i];
                    bi0[i] = l0 ? eIdx : bi0[i];
                }
            }
        }
        __syncthreads();
    }

    float* out_q = out;
    float* out_i = out + (size_t)M * ZD;
    float* out_l = out_i + M;

    #pragma unroll 1
    for (int i = 0; i < 4; ++i) {
        const long r = rbase + g * 4 + i;

        float gmin = bv0[i];
        #pragma unroll
        for (int o = 1; o < 16; o <<= 1) gmin = fminf(gmin, __shfl_xor(gmin, o, 64));
        const float thr = gmin + taur[i];

        unsigned b0 = (unsigned)(__ballot(bv0[i] <= thr) >> (g * 16)) & 0xFFFFu;
        unsigned b1 = (unsigned)(__ballot(bv1[i] <= thr) >> (g * 16)) & 0xFFFFu;
        unsigned b2 = (unsigned)(__ballot(bv2[i] <= thr) >> (g * 16)) & 0xFFFFu;
        unsigned b3 = (unsigned)(__ballot(bv3[i] <= thr) >> (g * 16)) & 0xFFFFu;
        const int cnt = __popc(b0) + __popc(b1) + __popc(b2) + __popc(b3);
        const bool ex = (b3 != 0u) || (cnt > 7);

        if (cnt == 1 && !ex) {
            // single in-window candidate: provably the argmin (tau > 2*Delta)
            if (bv0[i] <= thr) out_l[r] = (float)bi0[i];
        } else {
            float* rec = out_q + (size_t)r * ZD;
            if (!ex) {
                if (lg == 0) rec[0] = (float)cnt;
                const unsigned mlt = (1u << lg) - 1u;
                int base = 1;
                if (bv0[i] <= thr) rec[base + __popc(b0 & mlt)] = (float)bi0[i];
                base += __popc(b0);
                if (bv1[i] <= thr) rec[base + __popc(b1 & mlt)] = (float)bi1[i];
                base += __popc(b1);
                if (bv2[i] <= thr) rec[base + __popc(b2 & mlt)] = (float)bi2[i];
            }
            if (lg == 0) {
                int pos = atomicAdd(blkcnt, 1);    // LDS atomic, block-local
                out_q[(size_t)(rbase0 + pos) * ZD + 8] =
                    ex ? -(float)(r + 1) : (float)r;
            }
        }
    }
    __syncthreads();
    if (t == 0) out_q[(size_t)rbase0 * ZD + 10] = (float)(*blkcnt);
}

// ---------------------------------------------------------------------------
// K2a verify: one WAVE per worklist entry (R10 structure, new offsets).
// Wave stages h row + <=7 candidate e rows with coalesced 1KB loads into its
// LDS slice, lanes 0..cnt-1 run the bit-exact serial chains from LDS,
// 8-lane lex (d,idx) reduce == R1 semantics. besti -> out_l[r].
// ---------------------------------------------------------------------------
__global__ __launch_bounds__(256) void vq_verify(const float* __restrict__ h,
                                                 const float* __restrict__ emb,
                                                 const float* __restrict__ en,
                                                 float* __restrict__ out, int M) {
    extern __shared__ float Lall[];          // 4 waves x 8 rows x 260 floats
    const int t    = threadIdx.x;
    const int wv   = t >> 6;
    const int lane = t & 63;
    float* Lw = Lall + wv * (8 * 260);

    const int b   = blockIdx.x >> 1;
    const int sub = ((blockIdx.x & 1) << 2) | wv;   // 0..7
    const long rbase0 = (long)b * 256;

    float* out_q = out;
    float* out_i = out + (size_t)M * ZD;
    float* out_l = out_i + M;
    const float INF = __builtin_inff();

    const int count = (int)out_q[(size_t)rbase0 * ZD + 10];

    for (int j = sub; j < count; j += 8) {
        const float ef = out_q[(size_t)(rbase0 + j) * ZD + 8];
        const bool ex = ef < 0.f;
        const long r = ex ? (long)(-ef) - 1 : (long)ef;

        asm volatile("s_waitcnt lgkmcnt(0)" ::: "memory");  // WAR vs prev iter

        if (!ex) {
            const float* rec = out_q + (size_t)r * ZD;
            const float4 rA = *(const float4*)(rec);
            const float4 rB = *(const float4*)(rec + 4);
            const int cnt = (int)rA.x;
            const float hn = out_i[r];

            { // stage h row (coalesced 1KB)
                float4 v = *(const float4*)(h + (size_t)r * ZD + lane * 4);
                *(float4*)(Lw + lane * 4) = v;
            }
            #pragma unroll 1
            for (int q = 0; q < cnt; ++q) {   // stage candidate e rows
                const float fq = (q == 0) ? rA.y : (q == 1) ? rA.z : (q == 2) ? rA.w
                               : (q == 3) ? rB.x : (q == 4) ? rB.y : (q == 5) ? rB.z : rB.w;
                const int eidx = (int)fq;
                float4 v = *(const float4*)(emb + (size_t)eidx * ZD + lane * 4);
                *(float4*)(Lw + (1 + q) * 260 + lane * 4) = v;
            }
            asm volatile("s_waitcnt lgkmcnt(0)" ::: "memory");  // RAW

            float bd = INF;
            int   bi = 0x7FFFFFFF;
            if (lane < cnt) {
                const float fq = (lane == 0) ? rA.y : (lane == 1) ? rA.z : (lane == 2) ? rA.w
                               : (lane == 3) ? rB.x : (lane == 4) ? rB.y : (lane == 5) ? rB.z : rB.w;
                const int idx = (int)fq;
                const float* hl = Lw;
                const float* el = Lw + (1 + lane) * 260;
                float dot = 0.f;
                #pragma unroll 8
                for (int k = 0; k < ZD; k += 4) {
                    dot = fmaf(hl[k],     el[k],     dot);
                    dot = fmaf(hl[k + 1], el[k + 1], dot);
                    dot = fmaf(hl[k + 2], el[k + 2], dot);
                    dot = fmaf(hl[k + 3], el[k + 3], dot);
                }
                bd = __fsub_rn(__fadd_rn(hn, en[idx]), __fmul_rn(2.0f, dot));
                bi = idx;
            }
            #pragma unroll
            for (int o = 1; o < 8; o <<= 1) {  // lex (d,idx) min over lanes 0..7
                float ov = __shfl_xor(bd, o, 8);
                int   oi = __shfl_xor(bi, o, 8);
                if (ov < bd || (ov == bd && oi < bi)) { bd = ov; bi = oi; }
            }
            if (lane == 0) out_l[r] = (float)bi;
        } else {
            // exhaustive (ultra-rare): h from LDS, lane-parallel over entries
            const float hnx = out_i[r];
            {
                float4 v = *(const float4*)(h + (size_t)r * ZD + lane * 4);
                *(float4*)(Lw + lane * 4) = v;
            }
            asm volatile("s_waitcnt lgkmcnt(0)" ::: "memory");
            float bd = INF;
            int   bi = 0x7FFFFFFF;
            for (int e = lane; e < NE; e += 64) {
                const float* er = emb + (size_t)e * ZD;
                float dot = 0.f;
                #pragma unroll 8
                for (int k = 0; k < ZD; k += 4) {
                    float4 ev = *(const float4*)(er + k);
                    dot = fmaf(Lw[k],     ev.x, dot);
                    dot = fmaf(Lw[k + 1], ev.y, dot);
                    dot = fmaf(Lw[k + 2], ev.z, dot);
                    dot = fmaf(Lw[k + 3], ev.w, dot);
                }
                float dx = __fsub_rn(__fadd_rn(hnx, en[e]), __fmul_rn(2.0f, dot));
                if (dx < bd || (dx == bd && e < bi)) { bd = dx; bi = e; }
            }
            #pragma unroll
            for (int o = 1; o < 64; o <<= 1) {
                float ov = __shfl_xor(bd, o, 64);
                int   oi = __shfl_xor(bi, o, 64);
                if (ov < bd || (ov == bd && oi < bi)) { bd = ov; bi = oi; }
            }
            if (lane == 0) out_l[r] = (float)bi;
        }
    }
}

// ---------------------------------------------------------------------------
// K2b stream: pure-bandwidth epilogue at full TLP (8192 blocks). Reads besti
// from out_l[r] (read precedes the lg==0 overwrite), then R1's byte-exact
// epilogue: out_q / out_i / out_l.
// ---------------------------------------------------------------------------
__global__ __launch_bounds__(256) void vq_stream(const float* __restrict__ h,
                                                 const float* __restrict__ emb,
                                                 float* out, int M) {
    const int t    = threadIdx.x;
    const int lane = t & 63;
    const int wv   = t >> 6;      // 0..3
    const int g    = lane >> 4;   // 0..3
    const int lg   = lane & 15;
    const long r = (long)blockIdx.x * 16 + wv * 4 + g;

    float* out_q = out;
    float* out_i = out + (size_t)M * ZD;
    float* out_l = out_i + M;

    const int b = (int)out_l[r];
    const float* hrow = h + (size_t)r * ZD;
    const float* erow = emb + (size_t)b * ZD;
    float csum = 0.0f;
    #pragma unroll
    for (int q4 = 0; q4 < 4; ++q4) {
        int k = lg * 16 + q4 * 4;
        float4 hv = *(const float4*)(hrow + k);
        float4 ev = *(const float4*)(erow + k);
        float dx = __fsub_rn(ev.x, hv.x);
        float dy = __fsub_rn(ev.y, hv.y);
        float dz = __fsub_rn(ev.z, hv.z);
        float dw = __fsub_rn(ev.w, hv.w);
        float4 o;
        o.x = __fadd_rn(hv.x, dx);
        o.y = __fadd_rn(hv.y, dy);
        o.z = __fadd_rn(hv.z, dz);
        o.w = __fadd_rn(hv.w, dw);
        *(float4*)(out_q + (size_t)r * ZD + k) = o;
        csum = fmaf(dx, dx, csum);
        csum = fmaf(dy, dy, csum);
        csum = fmaf(dz, dz, csum);
        csum = fmaf(dw, dw, csum);
    }
    #pragma unroll
    for (int o2 = 1; o2 < 16; o2 <<= 1) csum += __shfl_xor(csum, o2, 64);
    if (lg == 0) {
        float cmean = csum * (1.0f / 256.0f);
        out_i[r] = (float)b;
        out_l[r] = __fadd_rn(__fmul_rn(cmean, 0.1f), __fmul_rn(cmean, 0.2f));
    }
}

extern "C" void kernel_launch(void* const* d_in, const int* in_sizes, int n_in,
                              void* d_out, int out_size, void* d_ws, size_t ws_size,
                              hipStream_t stream) {
    const float* h   = (const float*)d_in[0];
    const float* emb = (const float*)d_in[1];
    const int M = in_sizes[0] / ZD;   // 131072

    unsigned char* ebB = (unsigned char*)d_ws;               // 512 KB bf16 eh swizzled
    float* en = (float*)(ebB + (size_t)NP * ZD * 2);         // 4 KB

    float* out = (float*)d_out;
    float* hn = out + (size_t)M * ZD;                        // hn in out_i region

    prep_e<<<NP / 64, 64, 0, stream>>>(emb, ebB, en, out);
    prep_h<<<M / 64, 256, 0, stream>>>(h, hn);

    const size_t lds_bytes = 131072 + 512 + 16;
    (void)hipFuncSetAttribute((const void*)vq_main,
                              hipFuncAttributeMaxDynamicSharedMemorySize,
                              (int)lds_bytes);
    vq_main<<<M / 256, 1024, lds_bytes, stream>>>(h, emb, ebB, en, out, M);

    const size_t v_lds = 4 * 8 * 260 * sizeof(float);        // 33280 B
    vq_verify<<<(M / 256) * 2, 256, v_lds, stream>>>(h, emb, en, out, M);
    vq_stream<<<M / 16, 256, 0, stream>>>(h, emb, out, M);
}

// Round 12
// 1103.014 us; speedup vs baseline: 1.1131x; 1.1131x over previous
//
#include <hip/hip_runtime.h>

#define ZD 256    // Z_NH
#define NE 1000   // NUM_ENTRY
#define NP 1024   // padded entries

typedef __attribute__((ext_vector_type(8))) short short8;
typedef __attribute__((ext_vector_type(4))) float f32x4;

static __device__ __forceinline__ unsigned short f2bf(float x) {
    unsigned u = __float_as_uint(x);
    u = (u + 0x7FFFu + ((u >> 16) & 1u)) >> 16;
    return (unsigned short)u;
}
static __device__ __forceinline__ float bf2f(unsigned short u) {
    return __uint_as_float((unsigned)u << 16);
}

// ---------------------------------------------------------------------------
// prep_e: eh (bf16 swizzled, ws) + el (bf16 residual, swizzled, ws+512KB)
// + en exact pairwise. Same swizzle layout for both halves.
// ---------------------------------------------------------------------------
__global__ __launch_bounds__(64) void prep_e(const float* __restrict__ emb,
                                             unsigned char* __restrict__ ebB,
                                             unsigned char* __restrict__ elB,
                                             float* __restrict__ en) {
    int e = blockIdx.x * 64 + threadIdx.x;
    if (e >= NP) return;
    unsigned base = (unsigned)e * 512u;
    unsigned x = ((unsigned)e & 7u) << 4;
    if (e < NE) {
        const float* row = emb + (size_t)e * ZD;
        for (int k = 0; k < ZD; k += 2) {  // 2k%4==0, pair stays in same dword
            unsigned off = (base + 2u * k) ^ x;
            unsigned short h0 = f2bf(row[k]);
            unsigned short h1 = f2bf(row[k + 1]);
            *(unsigned short*)(ebB + off)     = h0;
            *(unsigned short*)(ebB + off + 2) = h1;
            *(unsigned short*)(elB + off)     = f2bf(__fsub_rn(row[k],     bf2f(h0)));
            *(unsigned short*)(elB + off + 2) = f2bf(__fsub_rn(row[k + 1], bf2f(h1)));
        }
        float r[8];
        #pragma unroll
        for (int j = 0; j < 8; ++j) { float v = row[j]; r[j] = __fmul_rn(v, v); }
        for (int i = 8; i < 128; i += 8)
            #pragma unroll
            for (int j = 0; j < 8; ++j) { float v = row[i + j]; r[j] = __fadd_rn(r[j], __fmul_rn(v, v)); }
        float s1 = __fadd_rn(__fadd_rn(__fadd_rn(r[0], r[1]), __fadd_rn(r[2], r[3])),
                             __fadd_rn(__fadd_rn(r[4], r[5]), __fadd_rn(r[6], r[7])));
        #pragma unroll
        for (int j = 0; j < 8; ++j) { float v = row[128 + j]; r[j] = __fmul_rn(v, v); }
        for (int i = 136; i < 256; i += 8)
            #pragma unroll
            for (int j = 0; j < 8; ++j) { float v = row[i + j]; r[j] = __fadd_rn(r[j], __fmul_rn(v, v)); }
        float s2 = __fadd_rn(__fadd_rn(__fadd_rn(r[0], r[1]), __fadd_rn(r[2], r[3])),
                             __fadd_rn(__fadd_rn(r[4], r[5]), __fadd_rn(r[6], r[7])));
        en[e] = __fadd_rn(s1, s2);
    } else {
        for (int k = 0; k < 128; ++k) {
            *(unsigned*)(ebB + base + 4u * k) = 0u;
            *(unsigned*)(elB + base + 4u * k) = 0u;
        }
        en[e] = __builtin_inff();
    }
}

// ---------------------------------------------------------------------------
// prep_h: hh (bf16) at out-row bytes 0..511, hl (bf16 residual) at bytes
// 512..1023 (the half R1 left unused), hn exact pairwise into out_i region.
// ---------------------------------------------------------------------------
__global__ __launch_bounds__(256) void prep_h(const float* __restrict__ h,
                                              unsigned short* __restrict__ hb,
                                              float* __restrict__ hn) {
    __shared__ float L[64][257];
    const int t = threadIdx.x;
    const long row0 = (long)blockIdx.x * 64;
    const int kq = (t & 63) * 4;
    const int rq = t >> 6;
    #pragma unroll
    for (int p = 0; p < 16; ++p) {
        int row = p * 4 + rq;
        float4 v = *(const float4*)(h + (row0 + row) * ZD + kq);
        L[row][kq] = v.x; L[row][kq + 1] = v.y; L[row][kq + 2] = v.z; L[row][kq + 3] = v.w;
    }
    __syncthreads();
    #pragma unroll
    for (int p = 0; p < 16; ++p) {
        int row = p * 4 + rq;
        ushort4 oh, ol;
        float a0 = L[row][kq],     a1 = L[row][kq + 1];
        float a2 = L[row][kq + 2], a3 = L[row][kq + 3];
        oh.x = f2bf(a0); oh.y = f2bf(a1); oh.z = f2bf(a2); oh.w = f2bf(a3);
        ol.x = f2bf(__fsub_rn(a0, bf2f(oh.x)));
        ol.y = f2bf(__fsub_rn(a1, bf2f(oh.y)));
        ol.z = f2bf(__fsub_rn(a2, bf2f(oh.z)));
        ol.w = f2bf(__fsub_rn(a3, bf2f(oh.w)));
        *(ushort4*)(hb + (row0 + row) * 512 + kq) = oh;
        *(ushort4*)(hb + (row0 + row) * 512 + 256 + kq) = ol;
    }
    if (t < 64) {
        float r[8];
        #pragma unroll
        for (int j = 0; j < 8; ++j) { float v = L[t][j]; r[j] = __fmul_rn(v, v); }
        for (int i = 8; i < 128; i += 8)
            #pragma unroll
            for (int j = 0; j < 8; ++j) { float v = L[t][i + j]; r[j] = __fadd_rn(r[j], __fmul_rn(v, v)); }
        float s1 = __fadd_rn(__fadd_rn(__fadd_rn(r[0], r[1]), __fadd_rn(r[2], r[3])),
                             __fadd_rn(__fadd_rn(r[4], r[5]), __fadd_rn(r[6], r[7])));
        #pragma unroll
        for (int j = 0; j < 8; ++j) { float v = L[t][128 + j]; r[j] = __fmul_rn(v, v); }
        for (int i = 136; i < 256; i += 8)
            #pragma unroll
            for (int j = 0; j < 8; ++j) { float v = L[t][i + j]; r[j] = __fadd_rn(r[j], __fmul_rn(v, v)); }
        float s2 = __fadd_rn(__fadd_rn(__fadd_rn(r[0], r[1]), __fadd_rn(r[2], r[3])),
                             __fadd_rn(__fadd_rn(r[4], r[5]), __fadd_rn(r[6], r[7])));
        hn[row0 + t] = __fadd_rn(s1, s2);
    }
}

// ---------------------------------------------------------------------------
// K1 main: split-precision bf16 MFMA (hh*eh + hh*el + hl*eh), approx error
// ~<1e-4 -> tau = 1e-6*sqrt(256*hn)+2.5e-4 (validated absmax=0 in R11) ->
// verify set ~2% of rows. A-frags loaded as short8 (R1-proven pattern, no
// in-kernel conversion -> no spill). 128-entry chunks x 8 (eh+el 128KB LDS).
// Epilogue: cnt==1 resolved here (out_l[r]=besti); others -> record (+0..7),
// worklist (+8 of row rbase0+pos), count (+10 of rbase0).
// ---------------------------------------------------------------------------
__global__ __launch_bounds__(1024, 4) void vq_main(const float* __restrict__ emb,
                                                   const unsigned char* __restrict__ ebB,
                                                   const unsigned char* __restrict__ elB,
                                                   const float* __restrict__ en,
                                                   float* out, int M) {
    extern __shared__ char lds[];
    char* BsEH = lds;                         // 65536 B eh chunk (swizzled)
    char* BsEL = lds + 65536;                 // 65536 B el chunk (swizzled)
    float* en_s = (float*)(lds + 131072);     // 128 floats
    int* blkcnt = (int*)(lds + 131072 + 512);

    const int t  = threadIdx.x;
    const int lane = t & 63;
    const int wv = t >> 6;                    // 0..15
    const int g  = lane >> 4;                 // 0..3
    const int lg = lane & 15;
    const long rbase = (long)blockIdx.x * 256 + wv * 16;
    const long rbase0 = (long)blockIdx.x * 256;

    const unsigned short* hb = (const unsigned short*)out;    // hh/hl rows
    const float* hnp = out + (size_t)M * ZD;  // hn values (out_i region)

    if (t == 0) *blkcnt = 0;

    // ---- A fragments: row rbase+lg, k = kt*32 + g*8 .. +8 (short8 loads) ----
    short8 hhf[8], hlf[8];
    {
        const unsigned short* hr = hb + (rbase + lg) * 512;
        #pragma unroll
        for (int kt = 0; kt < 8; ++kt) {
            hhf[kt] = *(const short8*)(hr + kt * 32 + g * 8);
            hlf[kt] = *(const short8*)(hr + 256 + kt * 32 + g * 8);
        }
    }
    float hnr[4], taur[4];
    #pragma unroll
    for (int i = 0; i < 4; ++i) {
        hnr[i] = hnp[rbase + g * 4 + i];
        // split-precision approx: |d_approx - d_exact| << 1e-4; tau >= 2*Delta
        taur[i] = 1.0e-6f * sqrtf(256.0f * hnr[i]) + 2.5e-4f;
    }

    const float INF = __builtin_inff();
    float bv0[4], bv1[4], bv2[4], bv3[4];
    int   bi0[4], bi1[4], bi2[4], bi3[4];
    #pragma unroll
    for (int i = 0; i < 4; ++i) {
        bv0[i] = INF; bv1[i] = INF; bv2[i] = INF; bv3[i] = INF;
        bi0[i] = 0;   bi1[i] = 0;   bi2[i] = 0;   bi3[i] = 0;
    }

    for (int c = 0; c < 8; ++c) {
        { // stage eh and el chunks linearly (coalesced, conflict-free)
            const uint4* srcEH = (const uint4*)(ebB + (size_t)c * 65536);
            const uint4* srcEL = (const uint4*)(elB + (size_t)c * 65536);
            uint4* dstEH = (uint4*)BsEH;
            uint4* dstEL = (uint4*)BsEL;
            #pragma unroll
            for (int p = 0; p < 4; ++p) dstEH[p * 1024 + t] = srcEH[p * 1024 + t];
            #pragma unroll
            for (int p = 0; p < 4; ++p) dstEL[p * 1024 + t] = srcEL[p * 1024 + t];
        }
        if (t < 32) {
            float4 v = *(const float4*)(en + c * 128 + t * 4);
            *(float4*)(en_s + t * 4) = v;
        }
        __syncthreads();

        for (int nt = 0; nt < 8; ++nt) {
            f32x4 a0 = {0.f, 0.f, 0.f, 0.f};   // hh*eh
            f32x4 a1 = {0.f, 0.f, 0.f, 0.f};   // hh*el
            f32x4 a2 = {0.f, 0.f, 0.f, 0.f};   // hl*eh
            const int nb = nt * 16 + lg;        // entry in chunk 0..127
            const unsigned x = ((unsigned)lg & 7u) << 4;
            const unsigned rowb = (unsigned)nb * 512u;
            #pragma unroll
            for (int kt = 0; kt < 8; ++kt) {
                const unsigned off = (rowb + (unsigned)kt * 64u + g * 16u) ^ x;
                short8 beh = *(const short8*)(BsEH + off);
                short8 bel = *(const short8*)(BsEL + off);
                a0 = __builtin_amdgcn_mfma_f32_16x16x32_bf16(hhf[kt], beh, a0, 0, 0, 0);
                a1 = __builtin_amdgcn_mfma_f32_16x16x32_bf16(hhf[kt], bel, a1, 0, 0, 0);
                a2 = __builtin_amdgcn_mfma_f32_16x16x32_bf16(hlf[kt], beh, a2, 0, 0, 0);
            }
            const int eIdx = c * 128 + nb;
            const float ene = en_s[nb];
            #pragma unroll
            for (int i = 0; i < 4; ++i) {
                float dot = __fadd_rn(__fadd_rn(a0[i], a1[i]), a2[i]);
                float d = __fsub_rn(__fadd_rn(hnr[i], ene), __fmul_rn(2.0f, dot));
                if (__any(d < bv3[i])) {
                    bool l3 = d < bv3[i], l2 = d < bv2[i], l1 = d < bv1[i], l0 = d < bv0[i];
                    bv3[i] = l3 ? (l2 ? bv2[i] : d) : bv3[i];
                    bi3[i] = l3 ? (l2 ? bi2[i] : eIdx) : bi3[i];
                    bv2[i] = l2 ? (l1 ? bv1[i] : d) : bv2[i];
                    bi2[i] = l2 ? (l1 ? bi1[i] : eIdx) : bi2[i];
                    bv1[i] = l1 ? (l0 ? bv0[i] : d) : bv1[i];
                    bi1[i] = l1 ? (l0 ? bi0[i] : eIdx) : bi1[i];
                    bv0[i] = l0 ? d : bv0[i];
                    bi0[i] = l0 ? eIdx : bi0[i];
                }
            }
        }
        __syncthreads();
    }

    float* out_q = out;
    float* out_i = out + (size_t)M * ZD;
    float* out_l = out_i + M;

    #pragma unroll 1
    for (int i = 0; i < 4; ++i) {
        const long r = rbase + g * 4 + i;

        float gmin = bv0[i];
        #pragma unroll
        for (int o = 1; o < 16; o <<= 1) gmin = fminf(gmin, __shfl_xor(gmin, o, 64));
        const float thr = gmin + taur[i];

        unsigned b0 = (unsigned)(__ballot(bv0[i] <= thr) >> (g * 16)) & 0xFFFFu;
        unsigned b1 = (unsigned)(__ballot(bv1[i] <= thr) >> (g * 16)) & 0xFFFFu;
        unsigned b2 = (unsigned)(__ballot(bv2[i] <= thr) >> (g * 16)) & 0xFFFFu;
        unsigned b3 = (unsigned)(__ballot(bv3[i] <= thr) >> (g * 16)) & 0xFFFFu;
        const int cnt = __popc(b0) + __popc(b1) + __popc(b2) + __popc(b3);
        const bool ex = (b3 != 0u) || (cnt > 7);

        if (cnt == 1 && !ex) {
            // single in-window candidate: provably the argmin (tau > 2*Delta)
            if (bv0[i] <= thr) out_l[r] = (float)bi0[i];
        } else {
            float* rec = out_q + (size_t)r * ZD;
            if (!ex) {
                if (lg == 0) rec[0] = (float)cnt;
                const unsigned mlt = (1u << lg) - 1u;
                int base = 1;
                if (bv0[i] <= thr) rec[base + __popc(b0 & mlt)] = (float)bi0[i];
                base += __popc(b0);
                if (bv1[i] <= thr) rec[base + __popc(b1 & mlt)] = (float)bi1[i];
                base += __popc(b1);
                if (bv2[i] <= thr) rec[base + __popc(b2 & mlt)] = (float)bi2[i];
            }
            if (lg == 0) {
                int pos = atomicAdd(blkcnt, 1);    // LDS atomic, block-local
                out_q[(size_t)(rbase0 + pos) * ZD + 8] =
                    ex ? -(float)(r + 1) : (float)r;
            }
        }
    }
    __syncthreads();
    if (t == 0) out_q[(size_t)rbase0 * ZD + 10] = (float)(*blkcnt);
}

// ---------------------------------------------------------------------------
// K2a verify: one WAVE per worklist entry (R10-proven structure). Wave stages
// h row + <=7 candidate e rows with coalesced 1KB loads into its LDS slice,
// lanes 0..cnt-1 run the bit-exact serial chains from LDS, 8-lane lex (d,idx)
// reduce == R1 semantics. besti -> out_l[r].
// ---------------------------------------------------------------------------
__global__ __launch_bounds__(256) void vq_verify(const float* __restrict__ h,
                                                 const float* __restrict__ emb,
                                                 const float* __restrict__ en,
                                                 float* __restrict__ out, int M) {
    extern __shared__ float Lall[];          // 4 waves x 8 rows x 260 floats
    const int t    = threadIdx.x;
    const int wv   = t >> 6;
    const int lane = t & 63;
    float* Lw = Lall + wv * (8 * 260);

    const int b   = blockIdx.x >> 1;
    const int sub = ((blockIdx.x & 1) << 2) | wv;   // 0..7
    const long rbase0 = (long)b * 256;

    float* out_q = out;
    float* out_i = out + (size_t)M * ZD;
    float* out_l = out_i + M;
    const float INF = __builtin_inff();

    const int count = (int)out_q[(size_t)rbase0 * ZD + 10];

    for (int j = sub; j < count; j += 8) {
        const float ef = out_q[(size_t)(rbase0 + j) * ZD + 8];
        const bool ex = ef < 0.f;
        const long r = ex ? (long)(-ef) - 1 : (long)ef;

        asm volatile("s_waitcnt lgkmcnt(0)" ::: "memory");  // WAR vs prev iter

        if (!ex) {
            const float* rec = out_q + (size_t)r * ZD;
            const float4 rA = *(const float4*)(rec);
            const float4 rB = *(const float4*)(rec + 4);
            const int cnt = (int)rA.x;
            const float hn = out_i[r];

            { // stage h row (coalesced 1KB)
                float4 v = *(const float4*)(h + (size_t)r * ZD + lane * 4);
                *(float4*)(Lw + lane * 4) = v;
            }
            #pragma unroll 1
            for (int q = 0; q < cnt; ++q) {   // stage candidate e rows
                const float fq = (q == 0) ? rA.y : (q == 1) ? rA.z : (q == 2) ? rA.w
                               : (q == 3) ? rB.x : (q == 4) ? rB.y : (q == 5) ? rB.z : rB.w;
                const int eidx = (int)fq;
                float4 v = *(const float4*)(emb + (size_t)eidx * ZD + lane * 4);
                *(float4*)(Lw + (1 + q) * 260 + lane * 4) = v;
            }
            asm volatile("s_waitcnt lgkmcnt(0)" ::: "memory");  // RAW

            float bd = INF;
            int   bi = 0x7FFFFFFF;
            if (lane < cnt) {
                const float fq = (lane == 0) ? rA.y : (lane == 1) ? rA.z : (lane == 2) ? rA.w
                               : (lane == 3) ? rB.x : (lane == 4) ? rB.y : (lane == 5) ? rB.z : rB.w;
                const int idx = (int)fq;
                const float* hl = Lw;
                const float* el = Lw + (1 + lane) * 260;
                float dot = 0.f;
                #pragma unroll 8
                for (int k = 0; k < ZD; k += 4) {
                    dot = fmaf(hl[k],     el[k],     dot);
                    dot = fmaf(hl[k + 1], el[k + 1], dot);
                    dot = fmaf(hl[k + 2], el[k + 2], dot);
                    dot = fmaf(hl[k + 3], el[k + 3], dot);
                }
                bd = __fsub_rn(__fadd_rn(hn, en[idx]), __fmul_rn(2.0f, dot));
                bi = idx;
            }
            #pragma unroll
            for (int o = 1; o < 8; o <<= 1) {  // lex (d,idx) min over lanes 0..7
                float ov = __shfl_xor(bd, o, 8);
                int   oi = __shfl_xor(bi, o, 8);
                if (ov < bd || (ov == bd && oi < bi)) { bd = ov; bi = oi; }
            }
            if (lane == 0) out_l[r] = (float)bi;
        } else {
            // exhaustive (ultra-rare): h from LDS, lane-parallel over entries
            const float hnx = out_i[r];
            {
                float4 v = *(const float4*)(h + (size_t)r * ZD + lane * 4);
                *(float4*)(Lw + lane * 4) = v;
            }
            asm volatile("s_waitcnt lgkmcnt(0)" ::: "memory");
            float bd = INF;
            int   bi = 0x7FFFFFFF;
            for (int e = lane; e < NE; e += 64) {
                const float* er = emb + (size_t)e * ZD;
                float dot = 0.f;
                #pragma unroll 8
                for (int k = 0; k < ZD; k += 4) {
                    float4 ev = *(const float4*)(er + k);
                    dot = fmaf(Lw[k],     ev.x, dot);
                    dot = fmaf(Lw[k + 1], ev.y, dot);
                    dot = fmaf(Lw[k + 2], ev.z, dot);
                    dot = fmaf(Lw[k + 3], ev.w, dot);
                }
                float dx = __fsub_rn(__fadd_rn(hnx, en[e]), __fmul_rn(2.0f, dot));
                if (dx < bd || (dx == bd && e < bi)) { bd = dx; bi = e; }
            }
            #pragma unroll
            for (int o = 1; o < 64; o <<= 1) {
                float ov = __shfl_xor(bd, o, 64);
                int   oi = __shfl_xor(bi, o, 64);
                if (ov < bd || (ov == bd && oi < bi)) { bd = ov; bi = oi; }
            }
            if (lane == 0) out_l[r] = (float)bi;
        }
    }
}

// ---------------------------------------------------------------------------
// K2b stream: pure-bandwidth epilogue at full TLP (8192 blocks). Reads besti
// from out_l[r] (read precedes the lg==0 overwrite), then R1's byte-exact
// epilogue: out_q / out_i / out_l.
// ---------------------------------------------------------------------------
__global__ __launch_bounds__(256) void vq_stream(const float* __restrict__ h,
                                                 const float* __restrict__ emb,
                                                 float* out, int M) {
    const int t    = threadIdx.x;
    const int lane = t & 63;
    const int wv   = t >> 6;      // 0..3
    const int g    = lane >> 4;   // 0..3
    const int lg   = lane & 15;
    const long r = (long)blockIdx.x * 16 + wv * 4 + g;

    float* out_q = out;
    float* out_i = out + (size_t)M * ZD;
    float* out_l = out_i + M;

    const int b = (int)out_l[r];
    const float* hrow = h + (size_t)r * ZD;
    const float* erow = emb + (size_t)b * ZD;
    float csum = 0.0f;
    #pragma unroll
    for (int q4 = 0; q4 < 4; ++q4) {
        int k = lg * 16 + q4 * 4;
        float4 hv = *(const float4*)(hrow + k);
        float4 ev = *(const float4*)(erow + k);
        float dx = __fsub_rn(ev.x, hv.x);
        float dy = __fsub_rn(ev.y, hv.y);
        float dz = __fsub_rn(ev.z, hv.z);
        float dw = __fsub_rn(ev.w, hv.w);
        float4 o;
        o.x = __fadd_rn(hv.x, dx);
        o.y = __fadd_rn(hv.y, dy);
        o.z = __fadd_rn(hv.z, dz);
        o.w = __fadd_rn(hv.w, dw);
        *(float4*)(out_q + (size_t)r * ZD + k) = o;
        csum = fmaf(dx, dx, csum);
        csum = fmaf(dy, dy, csum);
        csum = fmaf(dz, dz, csum);
        csum = fmaf(dw, dw, csum);
    }
    #pragma unroll
    for (int o2 = 1; o2 < 16; o2 <<= 1) csum += __shfl_xor(csum, o2, 64);
    if (lg == 0) {
        float cmean = csum * (1.0f / 256.0f);
        out_i[r] = (float)b;
        out_l[r] = __fadd_rn(__fmul_rn(cmean, 0.1f), __fmul_rn(cmean, 0.2f));
    }
}

extern "C" void kernel_launch(void* const* d_in, const int* in_sizes, int n_in,
                              void* d_out, int out_size, void* d_ws, size_t ws_size,
                              hipStream_t stream) {
    const float* h   = (const float*)d_in[0];
    const float* emb = (const float*)d_in[1];
    const int M = in_sizes[0] / ZD;   // 131072

    unsigned char* ebB = (unsigned char*)d_ws;               // 512 KB eh swizzled
    unsigned char* elB = ebB + (size_t)NP * ZD * 2;          // 512 KB el swizzled
    float* en = (float*)(elB + (size_t)NP * ZD * 2);         // 4 KB

    float* out = (float*)d_out;
    unsigned short* hb = (unsigned short*)d_out;             // hh/hl rows
    float* hn = out + (size_t)M * ZD;                        // hn in out_i region

    prep_e<<<NP / 64, 64, 0, stream>>>(emb, ebB, elB, en);
    prep_h<<<M / 64, 256, 0, stream>>>(h, hb, hn);

    const size_t lds_bytes = 131072 + 512 + 16;
    (void)hipFuncSetAttribute((const void*)vq_main,
                              hipFuncAttributeMaxDynamicSharedMemorySize,
                              (int)lds_bytes);
    vq_main<<<M / 256, 1024, lds_bytes, stream>>>(emb, ebB, elB, en, out, M);

    const size_t v_lds = 4 * 8 * 260 * sizeof(float);        // 33280 B
    vq_verify<<<(M / 256) * 2, 256, v_lds, stream>>>(h, emb, en, out, M);
    vq_stream<<<M / 16, 256, 0, stream>>>(h, emb, out, M);
}

// Round 13
// 873.487 us; speedup vs baseline: 1.4056x; 1.2628x over previous
//
#include <hip/hip_runtime.h>

#define ZD 256    // Z_NH
#define NE 1000   // NUM_ENTRY
#define NP 1024   // padded entries

typedef __attribute__((ext_vector_type(8))) short short8;
typedef __attribute__((ext_vector_type(4))) float f32x4;

static __device__ __forceinline__ unsigned short f2bf(float x) {
    unsigned u = __float_as_uint(x);
    u = (u + 0x7FFFu + ((u >> 16) & 1u)) >> 16;
    return (unsigned short)u;
}
static __device__ __forceinline__ float bf2f(unsigned short u) {
    return __uint_as_float((unsigned)u << 16);
}

// ---------------------------------------------------------------------------
// prep_e: eh (bf16 swizzled, ws) + el (bf16 residual, swizzled, ws+512KB)
// + en exact pairwise. Same swizzle layout for both halves.
// ---------------------------------------------------------------------------
__global__ __launch_bounds__(64) void prep_e(const float* __restrict__ emb,
                                             unsigned char* __restrict__ ebB,
                                             unsigned char* __restrict__ elB,
                                             float* __restrict__ en) {
    int e = blockIdx.x * 64 + threadIdx.x;
    if (e >= NP) return;
    unsigned base = (unsigned)e * 512u;
    unsigned x = ((unsigned)e & 7u) << 4;
    if (e < NE) {
        const float* row = emb + (size_t)e * ZD;
        for (int k = 0; k < ZD; k += 2) {  // 2k%4==0, pair stays in same dword
            unsigned off = (base + 2u * k) ^ x;
            unsigned short h0 = f2bf(row[k]);
            unsigned short h1 = f2bf(row[k + 1]);
            *(unsigned short*)(ebB + off)     = h0;
            *(unsigned short*)(ebB + off + 2) = h1;
            *(unsigned short*)(elB + off)     = f2bf(__fsub_rn(row[k],     bf2f(h0)));
            *(unsigned short*)(elB + off + 2) = f2bf(__fsub_rn(row[k + 1], bf2f(h1)));
        }
        float r[8];
        #pragma unroll
        for (int j = 0; j < 8; ++j) { float v = row[j]; r[j] = __fmul_rn(v, v); }
        for (int i = 8; i < 128; i += 8)
            #pragma unroll
            for (int j = 0; j < 8; ++j) { float v = row[i + j]; r[j] = __fadd_rn(r[j], __fmul_rn(v, v)); }
        float s1 = __fadd_rn(__fadd_rn(__fadd_rn(r[0], r[1]), __fadd_rn(r[2], r[3])),
                             __fadd_rn(__fadd_rn(r[4], r[5]), __fadd_rn(r[6], r[7])));
        #pragma unroll
        for (int j = 0; j < 8; ++j) { float v = row[128 + j]; r[j] = __fmul_rn(v, v); }
        for (int i = 136; i < 256; i += 8)
            #pragma unroll
            for (int j = 0; j < 8; ++j) { float v = row[i + j]; r[j] = __fadd_rn(r[j], __fmul_rn(v, v)); }
        float s2 = __fadd_rn(__fadd_rn(__fadd_rn(r[0], r[1]), __fadd_rn(r[2], r[3])),
                             __fadd_rn(__fadd_rn(r[4], r[5]), __fadd_rn(r[6], r[7])));
        en[e] = __fadd_rn(s1, s2);
    } else {
        for (int k = 0; k < 128; ++k) {
            *(unsigned*)(ebB + base + 4u * k) = 0u;
            *(unsigned*)(elB + base + 4u * k) = 0u;
        }
        en[e] = __builtin_inff();
    }
}

// ---------------------------------------------------------------------------
// prep_h: hh (bf16) rows in out_q region (R1-proven layout), hn exact
// pairwise into out_i region. No hl — 2-term split needs only hh frags.
// ---------------------------------------------------------------------------
__global__ __launch_bounds__(256) void prep_h(const float* __restrict__ h,
                                              unsigned short* __restrict__ hb,
                                              float* __restrict__ hn) {
    __shared__ float L[64][257];
    const int t = threadIdx.x;
    const long row0 = (long)blockIdx.x * 64;
    const int kq = (t & 63) * 4;
    const int rq = t >> 6;
    #pragma unroll
    for (int p = 0; p < 16; ++p) {
        int row = p * 4 + rq;
        float4 v = *(const float4*)(h + (row0 + row) * ZD + kq);
        L[row][kq] = v.x; L[row][kq + 1] = v.y; L[row][kq + 2] = v.z; L[row][kq + 3] = v.w;
    }
    __syncthreads();
    #pragma unroll
    for (int p = 0; p < 16; ++p) {
        int row = p * 4 + rq;
        ushort4 o;
        o.x = f2bf(L[row][kq]);     o.y = f2bf(L[row][kq + 1]);
        o.z = f2bf(L[row][kq + 2]); o.w = f2bf(L[row][kq + 3]);
        *(ushort4*)(hb + (row0 + row) * 512 + kq) = o;
    }
    if (t < 64) {
        float r[8];
        #pragma unroll
        for (int j = 0; j < 8; ++j) { float v = L[t][j]; r[j] = __fmul_rn(v, v); }
        for (int i = 8; i < 128; i += 8)
            #pragma unroll
            for (int j = 0; j < 8; ++j) { float v = L[t][i + j]; r[j] = __fadd_rn(r[j], __fmul_rn(v, v)); }
        float s1 = __fadd_rn(__fadd_rn(__fadd_rn(r[0], r[1]), __fadd_rn(r[2], r[3])),
                             __fadd_rn(__fadd_rn(r[4], r[5]), __fadd_rn(r[6], r[7])));
        #pragma unroll
        for (int j = 0; j < 8; ++j) { float v = L[t][128 + j]; r[j] = __fmul_rn(v, v); }
        for (int i = 136; i < 256; i += 8)
            #pragma unroll
            for (int j = 0; j < 8; ++j) { float v = L[t][i + j]; r[j] = __fadd_rn(r[j], __fmul_rn(v, v)); }
        float s2 = __fadd_rn(__fadd_rn(__fadd_rn(r[0], r[1]), __fadd_rn(r[2], r[3])),
                             __fadd_rn(__fadd_rn(r[4], r[5]), __fadd_rn(r[6], r[7])));
        hn[row0 + t] = __fadd_rn(s1, s2);
    }
}

// ---------------------------------------------------------------------------
// K1 main: 2-term split-precision MFMA: dot ~= hh*eh + hh*el = hh*e.
// Dropped term hl*e <= 2^-9*sqrt(hn)*sqrt(en) <= 3.1e-5*sqrt(hn) worst-case;
// tau = 7e-5*sqrt(hn)+2.5e-4 >= 2*Delta (provably sound) -> verify ~18%.
// ONLY hh frags (32 regs) -> R1's proven register footprint, no spill.
// MFMA count identical to R1 (1024/wave). 128-entry chunks x 8, eh+el LDS.
// Epilogue: cnt==1 resolved here (out_l[r]=besti); others -> record (+0..7),
// worklist (+8 of row rbase0+pos), count (+10 of rbase0).
// ---------------------------------------------------------------------------
__global__ __launch_bounds__(1024, 4) void vq_main(const unsigned char* __restrict__ ebB,
                                                   const unsigned char* __restrict__ elB,
                                                   const float* __restrict__ en,
                                                   float* out, int M) {
    extern __shared__ char lds[];
    char* BsEH = lds;                         // 65536 B eh chunk (swizzled)
    char* BsEL = lds + 65536;                 // 65536 B el chunk (swizzled)
    float* en_s = (float*)(lds + 131072);     // 128 floats
    int* blkcnt = (int*)(lds + 131072 + 512);

    const int t  = threadIdx.x;
    const int lane = t & 63;
    const int wv = t >> 6;                    // 0..15
    const int g  = lane >> 4;                 // 0..3
    const int lg = lane & 15;
    const long rbase = (long)blockIdx.x * 256 + wv * 16;
    const long rbase0 = (long)blockIdx.x * 256;

    const unsigned short* hb = (const unsigned short*)out;    // hh rows
    const float* hnp = out + (size_t)M * ZD;  // hn values (out_i region)

    if (t == 0) *blkcnt = 0;

    // ---- A fragments: row rbase+lg, k = kt*32 + g*8 .. +8 (R1 pattern) ----
    short8 hhf[8];
    {
        const unsigned short* hr = hb + (rbase + lg) * 512;
        #pragma unroll
        for (int kt = 0; kt < 8; ++kt)
            hhf[kt] = *(const short8*)(hr + kt * 32 + g * 8);
    }
    float hnr[4], taur[4];
    #pragma unroll
    for (int i = 0; i < 4; ++i) {
        hnr[i] = hnp[rbase + g * 4 + i];
        // 2-term split: Delta <= 3.1e-5*sqrt(hn) + ~1e-4; tau >= 2*Delta
        taur[i] = 7.0e-5f * sqrtf(hnr[i]) + 2.5e-4f;
    }

    const float INF = __builtin_inff();
    float bv0[4], bv1[4], bv2[4], bv3[4];
    int   bi0[4], bi1[4], bi2[4], bi3[4];
    #pragma unroll
    for (int i = 0; i < 4; ++i) {
        bv0[i] = INF; bv1[i] = INF; bv2[i] = INF; bv3[i] = INF;
        bi0[i] = 0;   bi1[i] = 0;   bi2[i] = 0;   bi3[i] = 0;
    }

    for (int c = 0; c < 8; ++c) {
        { // stage eh and el chunks linearly (coalesced, conflict-free)
            const uint4* srcEH = (const uint4*)(ebB + (size_t)c * 65536);
            const uint4* srcEL = (const uint4*)(elB + (size_t)c * 65536);
            uint4* dstEH = (uint4*)BsEH;
            uint4* dstEL = (uint4*)BsEL;
            #pragma unroll
            for (int p = 0; p < 4; ++p) dstEH[p * 1024 + t] = srcEH[p * 1024 + t];
            #pragma unroll
            for (int p = 0; p < 4; ++p) dstEL[p * 1024 + t] = srcEL[p * 1024 + t];
        }
        if (t < 32) {
            float4 v = *(const float4*)(en + c * 128 + t * 4);
            *(float4*)(en_s + t * 4) = v;
        }
        __syncthreads();

        for (int nt = 0; nt < 8; ++nt) {
            f32x4 a0 = {0.f, 0.f, 0.f, 0.f};   // hh*eh
            f32x4 a1 = {0.f, 0.f, 0.f, 0.f};   // hh*el
            const int nb = nt * 16 + lg;        // entry in chunk 0..127
            const unsigned x = ((unsigned)lg & 7u) << 4;
            const unsigned rowb = (unsigned)nb * 512u;
            #pragma unroll
            for (int kt = 0; kt < 8; ++kt) {
                const unsigned off = (rowb + (unsigned)kt * 64u + g * 16u) ^ x;
                short8 beh = *(const short8*)(BsEH + off);
                short8 bel = *(const short8*)(BsEL + off);
                a0 = __builtin_amdgcn_mfma_f32_16x16x32_bf16(hhf[kt], beh, a0, 0, 0, 0);
                a1 = __builtin_amdgcn_mfma_f32_16x16x32_bf16(hhf[kt], bel, a1, 0, 0, 0);
            }
            const int eIdx = c * 128 + nb;
            const float ene = en_s[nb];
            #pragma unroll
            for (int i = 0; i < 4; ++i) {
                float dot = __fadd_rn(a0[i], a1[i]);
                float d = __fsub_rn(__fadd_rn(hnr[i], ene), __fmul_rn(2.0f, dot));
                if (__any(d < bv3[i])) {
                    bool l3 = d < bv3[i], l2 = d < bv2[i], l1 = d < bv1[i], l0 = d < bv0[i];
                    bv3[i] = l3 ? (l2 ? bv2[i] : d) : bv3[i];
                    bi3[i] = l3 ? (l2 ? bi2[i] : eIdx) : bi3[i];
                    bv2[i] = l2 ? (l1 ? bv1[i] : d) : bv2[i];
                    bi2[i] = l2 ? (l1 ? bi1[i] : eIdx) : bi2[i];
                    bv1[i] = l1 ? (l0 ? bv0[i] : d) : bv1[i];
                    bi1[i] = l1 ? (l0 ? bi0[i] : eIdx) : bi1[i];
                    bv0[i] = l0 ? d : bv0[i];
                    bi0[i] = l0 ? eIdx : bi0[i];
                }
            }
        }
        __syncthreads();
    }

    float* out_q = out;
    float* out_i = out + (size_t)M * ZD;
    float* out_l = out_i + M;

    #pragma unroll 1
    for (int i = 0; i < 4; ++i) {
        const long r = rbase + g * 4 + i;

        float gmin = bv0[i];
        #pragma unroll
        for (int o = 1; o < 16; o <<= 1) gmin = fminf(gmin, __shfl_xor(gmin, o, 64));
        const float thr = gmin + taur[i];

        unsigned b0 = (unsigned)(__ballot(bv0[i] <= thr) >> (g * 16)) & 0xFFFFu;
        unsigned b1 = (unsigned)(__ballot(bv1[i] <= thr) >> (g * 16)) & 0xFFFFu;
        unsigned b2 = (unsigned)(__ballot(bv2[i] <= thr) >> (g * 16)) & 0xFFFFu;
        unsigned b3 = (unsigned)(__ballot(bv3[i] <= thr) >> (g * 16)) & 0xFFFFu;
        const int cnt = __popc(b0) + __popc(b1) + __popc(b2) + __popc(b3);
        const bool ex = (b3 != 0u) || (cnt > 7);

        if (cnt == 1 && !ex) {
            // single in-window candidate: provably the argmin (tau > 2*Delta)
            if (bv0[i] <= thr) out_l[r] = (float)bi0[i];
        } else {
            float* rec = out_q + (size_t)r * ZD;
            if (!ex) {
                if (lg == 0) rec[0] = (float)cnt;
                const unsigned mlt = (1u << lg) - 1u;
                int base = 1;
                if (bv0[i] <= thr) rec[base + __popc(b0 & mlt)] = (float)bi0[i];
                base += __popc(b0);
                if (bv1[i] <= thr) rec[base + __popc(b1 & mlt)] = (float)bi1[i];
                base += __popc(b1);
                if (bv2[i] <= thr) rec[base + __popc(b2 & mlt)] = (float)bi2[i];
            }
            if (lg == 0) {
                int pos = atomicAdd(blkcnt, 1);    // LDS atomic, block-local
                out_q[(size_t)(rbase0 + pos) * ZD + 8] =
                    ex ? -(float)(r + 1) : (float)r;
            }
        }
    }
    __syncthreads();
    if (t == 0) out_q[(size_t)rbase0 * ZD + 10] = (float)(*blkcnt);
}

// ---------------------------------------------------------------------------
// K2a verify: one WAVE per worklist entry (R10-proven structure). Wave stages
// h row + <=7 candidate e rows with coalesced 1KB loads into its LDS slice,
// lanes 0..cnt-1 run the bit-exact serial chains from LDS, 8-lane lex (d,idx)
// reduce == R1 semantics. besti -> out_l[r].
// ---------------------------------------------------------------------------
__global__ __launch_bounds__(256) void vq_verify(const float* __restrict__ h,
                                                 const float* __restrict__ emb,
                                                 const float* __restrict__ en,
                                                 float* __restrict__ out, int M) {
    extern __shared__ float Lall[];          // 4 waves x 8 rows x 260 floats
    const int t    = threadIdx.x;
    const int wv   = t >> 6;
    const int lane = t & 63;
    float* Lw = Lall + wv * (8 * 260);

    const int b   = blockIdx.x >> 1;
    const int sub = ((blockIdx.x & 1) << 2) | wv;   // 0..7
    const long rbase0 = (long)b * 256;

    float* out_q = out;
    float* out_i = out + (size_t)M * ZD;
    float* out_l = out_i + M;
    const float INF = __builtin_inff();

    const int count = (int)out_q[(size_t)rbase0 * ZD + 10];

    for (int j = sub; j < count; j += 8) {
        const float ef = out_q[(size_t)(rbase0 + j) * ZD + 8];
        const bool ex = ef < 0.f;
        const long r = ex ? (long)(-ef) - 1 : (long)ef;

        asm volatile("s_waitcnt lgkmcnt(0)" ::: "memory");  // WAR vs prev iter

        if (!ex) {
            const float* rec = out_q + (size_t)r * ZD;
            const float4 rA = *(const float4*)(rec);
            const float4 rB = *(const float4*)(rec + 4);
            const int cnt = (int)rA.x;
            const float hn = out_i[r];

            { // stage h row (coalesced 1KB)
                float4 v = *(const float4*)(h + (size_t)r * ZD + lane * 4);
                *(float4*)(Lw + lane * 4) = v;
            }
            #pragma unroll 1
            for (int q = 0; q < cnt; ++q) {   // stage candidate e rows
                const float fq = (q == 0) ? rA.y : (q == 1) ? rA.z : (q == 2) ? rA.w
                               : (q == 3) ? rB.x : (q == 4) ? rB.y : (q == 5) ? rB.z : rB.w;
                const int eidx = (int)fq;
                float4 v = *(const float4*)(emb + (size_t)eidx * ZD + lane * 4);
                *(float4*)(Lw + (1 + q) * 260 + lane * 4) = v;
            }
            asm volatile("s_waitcnt lgkmcnt(0)" ::: "memory");  // RAW

            float bd = INF;
            int   bi = 0x7FFFFFFF;
            if (lane < cnt) {
                const float fq = (lane == 0) ? rA.y : (lane == 1) ? rA.z : (lane == 2) ? rA.w
                               : (lane == 3) ? rB.x : (lane == 4) ? rB.y : (lane == 5) ? rB.z : rB.w;
                const int idx = (int)fq;
                const float* hl = Lw;
                const float* el = Lw + (1 + lane) * 260;
                float dot = 0.f;
                #pragma unroll 8
                for (int k = 0; k < ZD; k += 4) {
                    dot = fmaf(hl[k],     el[k],     dot);
                    dot = fmaf(hl[k + 1], el[k + 1], dot);
                    dot = fmaf(hl[k + 2], el[k + 2], dot);
                    dot = fmaf(hl[k + 3], el[k + 3], dot);
                }
                bd = __fsub_rn(__fadd_rn(hn, en[idx]), __fmul_rn(2.0f, dot));
                bi = idx;
            }
            #pragma unroll
            for (int o = 1; o < 8; o <<= 1) {  // lex (d,idx) min over lanes 0..7
                float ov = __shfl_xor(bd, o, 8);
                int   oi = __shfl_xor(bi, o, 8);
                if (ov < bd || (ov == bd && oi < bi)) { bd = ov; bi = oi; }
            }
            if (lane == 0) out_l[r] = (float)bi;
        } else {
            // exhaustive (ultra-rare): h from LDS, lane-parallel over entries
            const float hnx = out_i[r];
            {
                float4 v = *(const float4*)(h + (size_t)r * ZD + lane * 4);
                *(float4*)(Lw + lane * 4) = v;
            }
            asm volatile("s_waitcnt lgkmcnt(0)" ::: "memory");
            float bd = INF;
            int   bi = 0x7FFFFFFF;
            for (int e = lane; e < NE; e += 64) {
                const float* er = emb + (size_t)e * ZD;
                float dot = 0.f;
                #pragma unroll 8
                for (int k = 0; k < ZD; k += 4) {
                    float4 ev = *(const float4*)(er + k);
                    dot = fmaf(Lw[k],     ev.x, dot);
                    dot = fmaf(Lw[k + 1], ev.y, dot);
                    dot = fmaf(Lw[k + 2], ev.z, dot);
                    dot = fmaf(Lw[k + 3], ev.w, dot);
                }
                float dx = __fsub_rn(__fadd_rn(hnx, en[e]), __fmul_rn(2.0f, dot));
                if (dx < bd || (dx == bd && e < bi)) { bd = dx; bi = e; }
            }
            #pragma unroll
            for (int o = 1; o < 64; o <<= 1) {
                float ov = __shfl_xor(bd, o, 64);
                int   oi = __shfl_xor(bi, o, 64);
                if (ov < bd || (ov == bd && oi < bi)) { bd = ov; bi = oi; }
            }
            if (lane == 0) out_l[r] = (float)bi;
        }
    }
}

// ---------------------------------------------------------------------------
// K2b stream: pure-bandwidth epilogue at full TLP (8192 blocks). Reads besti
// from out_l[r] (read precedes the lg==0 overwrite), then R1's byte-exact
// epilogue: out_q / out_i / out_l.
// ---------------------------------------------------------------------------
__global__ __launch_bounds__(256) void vq_stream(const float* __restrict__ h,
                                                 const float* __restrict__ emb,
                                                 float* out, int M) {
    const int t    = threadIdx.x;
    const int lane = t & 63;
    const int wv   = t >> 6;      // 0..3
    const int g    = lane >> 4;   // 0..3
    const int lg   = lane & 15;
    const long r = (long)blockIdx.x * 16 + wv * 4 + g;

    float* out_q = out;
    float* out_i = out + (size_t)M * ZD;
    float* out_l = out_i + M;

    const int b = (int)out_l[r];
    const float* hrow = h + (size_t)r * ZD;
    const float* erow = emb + (size_t)b * ZD;
    float csum = 0.0f;
    #pragma unroll
    for (int q4 = 0; q4 < 4; ++q4) {
        int k = lg * 16 + q4 * 4;
        float4 hv = *(const float4*)(hrow + k);
        float4 ev = *(const float4*)(erow + k);
        float dx = __fsub_rn(ev.x, hv.x);
        float dy = __fsub_rn(ev.y, hv.y);
        float dz = __fsub_rn(ev.z, hv.z);
        float dw = __fsub_rn(ev.w, hv.w);
        float4 o;
        o.x = __fadd_rn(hv.x, dx);
        o.y = __fadd_rn(hv.y, dy);
        o.z = __fadd_rn(hv.z, dz);
        o.w = __fadd_rn(hv.w, dw);
        *(float4*)(out_q + (size_t)r * ZD + k) = o;
        csum = fmaf(dx, dx, csum);
        csum = fmaf(dy, dy, csum);
        csum = fmaf(dz, dz, csum);
        csum = fmaf(dw, dw, csum);
    }
    #pragma unroll
    for (int o2 = 1; o2 < 16; o2 <<= 1) csum += __shfl_xor(csum, o2, 64);
    if (lg == 0) {
        float cmean = csum * (1.0f / 256.0f);
        out_i[r] = (float)b;
        out_l[r] = __fadd_rn(__fmul_rn(cmean, 0.1f), __fmul_rn(cmean, 0.2f));
    }
}

extern "C" void kernel_launch(void* const* d_in, const int* in_sizes, int n_in,
                              void* d_out, int out_size, void* d_ws, size_t ws_size,
                              hipStream_t stream) {
    const float* h   = (const float*)d_in[0];
    const float* emb = (const float*)d_in[1];
    const int M = in_sizes[0] / ZD;   // 131072

    unsigned char* ebB = (unsigned char*)d_ws;               // 512 KB eh swizzled
    unsigned char* elB = ebB + (size_t)NP * ZD * 2;          // 512 KB el swizzled
    float* en = (float*)(elB + (size_t)NP * ZD * 2);         // 4 KB

    float* out = (float*)d_out;
    unsigned short* hb = (unsigned short*)d_out;             // hh rows
    float* hn = out + (size_t)M * ZD;                        // hn in out_i region

    prep_e<<<NP / 64, 64, 0, stream>>>(emb, ebB, elB, en);
    prep_h<<<M / 64, 256, 0, stream>>>(h, hb, hn);

    const size_t lds_bytes = 131072 + 512 + 16;
    (void)hipFuncSetAttribute((const void*)vq_main,
                              hipFuncAttributeMaxDynamicSharedMemorySize,
                              (int)lds_bytes);
    vq_main<<<M / 256, 1024, lds_bytes, stream>>>(ebB, elB, en, out, M);

    const size_t v_lds = 4 * 8 * 260 * sizeof(float);        // 33280 B
    vq_verify<<<(M / 256) * 2, 256, v_lds, stream>>>(h, emb, en, out, M);
    vq_stream<<<M / 16, 256, 0, stream>>>(h, emb, out, M);
}

// Round 14
// 507.792 us; speedup vs baseline: 2.4178x; 1.7202x over previous
//
#include <hip/hip_runtime.h>

#define ZD 256    // Z_NH
#define NE 1000   // NUM_ENTRY
#define NP 1024   // padded entries

typedef __attribute__((ext_vector_type(8))) short short8;
typedef __attribute__((ext_vector_type(4))) float f32x4;

static __device__ __forceinline__ unsigned short f2bf(float x) {
    unsigned u = __float_as_uint(x);
    u = (u + 0x7FFFu + ((u >> 16) & 1u)) >> 16;
    return (unsigned short)u;
}

// ---------------------------------------------------------------------------
// prep_e: eb (bf16, pre-XOR-swizzled within each 512B row) + en exact pairwise
// (R10 version, proven)
// ---------------------------------------------------------------------------
__global__ __launch_bounds__(64) void prep_e(const float* __restrict__ emb,
                                             unsigned char* __restrict__ ebB,
                                             float* __restrict__ en) {
    int e = blockIdx.x * 64 + threadIdx.x;
    if (e >= NP) return;
    unsigned base = (unsigned)e * 512u;
    unsigned x = ((unsigned)e & 7u) << 4;
    if (e < NE) {
        const float* row = emb + (size_t)e * ZD;
        for (int k = 0; k < ZD; k += 2) {  // 2k%4==0, pair stays in same dword
            unsigned off = (base + 2u * k) ^ x;
            *(unsigned short*)(ebB + off)     = f2bf(row[k]);
            *(unsigned short*)(ebB + off + 2) = f2bf(row[k + 1]);
        }
        float r[8];
        #pragma unroll
        for (int j = 0; j < 8; ++j) { float v = row[j]; r[j] = __fmul_rn(v, v); }
        for (int i = 8; i < 128; i += 8)
            #pragma unroll
            for (int j = 0; j < 8; ++j) { float v = row[i + j]; r[j] = __fadd_rn(r[j], __fmul_rn(v, v)); }
        float s1 = __fadd_rn(__fadd_rn(__fadd_rn(r[0], r[1]), __fadd_rn(r[2], r[3])),
                             __fadd_rn(__fadd_rn(r[4], r[5]), __fadd_rn(r[6], r[7])));
        #pragma unroll
        for (int j = 0; j < 8; ++j) { float v = row[128 + j]; r[j] = __fmul_rn(v, v); }
        for (int i = 136; i < 256; i += 8)
            #pragma unroll
            for (int j = 0; j < 8; ++j) { float v = row[i + j]; r[j] = __fadd_rn(r[j], __fmul_rn(v, v)); }
        float s2 = __fadd_rn(__fadd_rn(__fadd_rn(r[0], r[1]), __fadd_rn(r[2], r[3])),
                             __fadd_rn(__fadd_rn(r[4], r[5]), __fadd_rn(r[6], r[7])));
        en[e] = __fadd_rn(s1, s2);
    } else {
        for (int k = 0; k < 128; ++k) *(unsigned*)(ebB + base + 4u * k) = 0u;
        en[e] = __builtin_inff();
    }
}

// ---------------------------------------------------------------------------
// prep_h: hb (bf16 rows, stored in out_q region, row stride 512 ushorts) and
// hn (exact numpy-pairwise, stored in out_i region as float bits) — R10 ver.
// ---------------------------------------------------------------------------
__global__ __launch_bounds__(256) void prep_h(const float* __restrict__ h,
                                              unsigned short* __restrict__ hb,
                                              float* __restrict__ hn) {
    __shared__ float L[64][257];
    const int t = threadIdx.x;
    const long row0 = (long)blockIdx.x * 64;
    const int kq = (t & 63) * 4;
    const int rq = t >> 6;
    #pragma unroll
    for (int p = 0; p < 16; ++p) {
        int row = p * 4 + rq;
        float4 v = *(const float4*)(h + (row0 + row) * ZD + kq);
        L[row][kq] = v.x; L[row][kq + 1] = v.y; L[row][kq + 2] = v.z; L[row][kq + 3] = v.w;
    }
    __syncthreads();
    #pragma unroll
    for (int p = 0; p < 16; ++p) {
        int row = p * 4 + rq;
        ushort4 o;
        o.x = f2bf(L[row][kq]);     o.y = f2bf(L[row][kq + 1]);
        o.z = f2bf(L[row][kq + 2]); o.w = f2bf(L[row][kq + 3]);
        *(ushort4*)(hb + (row0 + row) * 512 + kq) = o;
    }
    if (t < 64) {
        float r[8];
        #pragma unroll
        for (int j = 0; j < 8; ++j) { float v = L[t][j]; r[j] = __fmul_rn(v, v); }
        for (int i = 8; i < 128; i += 8)
            #pragma unroll
            for (int j = 0; j < 8; ++j) { float v = L[t][i + j]; r[j] = __fadd_rn(r[j], __fmul_rn(v, v)); }
        float s1 = __fadd_rn(__fadd_rn(__fadd_rn(r[0], r[1]), __fadd_rn(r[2], r[3])),
                             __fadd_rn(__fadd_rn(r[4], r[5]), __fadd_rn(r[6], r[7])));
        #pragma unroll
        for (int j = 0; j < 8; ++j) { float v = L[t][128 + j]; r[j] = __fmul_rn(v, v); }
        for (int i = 136; i < 256; i += 8)
            #pragma unroll
            for (int j = 0; j < 8; ++j) { float v = L[t][i + j]; r[j] = __fadd_rn(r[j], __fmul_rn(v, v)); }
        float s2 = __fadd_rn(__fadd_rn(__fadd_rn(r[0], r[1]), __fadd_rn(r[2], r[3])),
                             __fadd_rn(__fadd_rn(r[4], r[5]), __fadd_rn(r[6], r[7])));
        hn[row0 + t] = __fadd_rn(s1, s2);
    }
}

// ---------------------------------------------------------------------------
// K1 main: R10's proven kernel (R1 main loop, 4x128KB chunks, guarded insert).
// Epilogue simplified: per row write ONE marker to out_l[r]:
//   cnt==1  -> besti (>=0, exact answer, no verification needed)
//   verify  -> -(float)cnt  (record with candidate indices at out_q row +0..7)
//   exhaust -> -99.0f
// No worklist, no LDS atomic.
// ---------------------------------------------------------------------------
__global__ __launch_bounds__(1024, 4) void vq_main(const float* __restrict__ h,
                                                   const float* __restrict__ emb,
                                                   const unsigned char* __restrict__ ebB,
                                                   const float* __restrict__ en,
                                                   float* out, int M) {
    extern __shared__ char lds[];
    char* BsB = lds;                          // 131072 B swizzled bf16 chunk
    float* en_s = (float*)(lds + 131072);     // 256 floats

    const int t  = threadIdx.x;
    const int lane = t & 63;
    const int wv = t >> 6;                    // 0..15
    const int g  = lane >> 4;                 // 0..3
    const int lg = lane & 15;
    const long rbase = (long)blockIdx.x * 256 + wv * 16;

    const unsigned short* hb = (const unsigned short*)out;    // bf16 h rows
    const float* hnp = out + (size_t)M * ZD;                  // hn values

    short8 afrag[8];
    {
        const unsigned short* hr = hb + (rbase + lg) * 512;
        #pragma unroll
        for (int kt = 0; kt < 8; ++kt)
            afrag[kt] = *(const short8*)(hr + kt * 32 + g * 8);
    }
    float hnr[4], taur[4];
    #pragma unroll
    for (int i = 0; i < 4; ++i) {
        hnr[i] = hnp[rbase + g * 4 + i];
        taur[i] = 1.0e-5f * sqrtf(256.0f * hnr[i]) + 1.0e-3f;
    }

    const float INF = __builtin_inff();
    float bv0[4], bv1[4], bv2[4], bv3[4];
    int   bi0[4], bi1[4], bi2[4], bi3[4];
    #pragma unroll
    for (int i = 0; i < 4; ++i) {
        bv0[i] = INF; bv1[i] = INF; bv2[i] = INF; bv3[i] = INF;
        bi0[i] = 0;   bi1[i] = 0;   bi2[i] = 0;   bi3[i] = 0;
    }

    for (int c = 0; c < 4; ++c) {
        {
            const uint4* src = (const uint4*)(ebB + (size_t)c * 131072);
            uint4* dst = (uint4*)BsB;
            #pragma unroll
            for (int p = 0; p < 8; ++p) dst[p * 1024 + t] = src[p * 1024 + t];
        }
        if (t < 64) {
            float4 v = *(const float4*)(en + c * 256 + t * 4);
            *(float4*)(en_s + t * 4) = v;
        }
        __syncthreads();

        for (int nt = 0; nt < 16; ++nt) {
            f32x4 acc0 = {0.f, 0.f, 0.f, 0.f};
            f32x4 acc1 = {0.f, 0.f, 0.f, 0.f};
            const int nb = nt * 16 + lg;
            const unsigned x = ((unsigned)lg & 7u) << 4;
            const unsigned rowb = (unsigned)nb * 512u;
            #pragma unroll
            for (int kt = 0; kt < 4; ++kt) {
                short8 b0 = *(const short8*)(BsB + ((rowb + (unsigned)kt * 64u + g * 16u) ^ x));
                short8 b1 = *(const short8*)(BsB + ((rowb + (unsigned)(kt + 4) * 64u + g * 16u) ^ x));
                acc0 = __builtin_amdgcn_mfma_f32_16x16x32_bf16(afrag[kt],     b0, acc0, 0, 0, 0);
                acc1 = __builtin_amdgcn_mfma_f32_16x16x32_bf16(afrag[kt + 4], b1, acc1, 0, 0, 0);
            }
            const int eIdx = c * 256 + nb;
            const float ene = en_s[nb];
            #pragma unroll
            for (int i = 0; i < 4; ++i) {
                float dot = __fadd_rn(acc0[i], acc1[i]);
                float d = __fsub_rn(__fadd_rn(hnr[i], ene), __fmul_rn(2.0f, dot));
                if (__any(d < bv3[i])) {
                    bool l3 = d < bv3[i], l2 = d < bv2[i], l1 = d < bv1[i], l0 = d < bv0[i];
                    bv3[i] = l3 ? (l2 ? bv2[i] : d) : bv3[i];
                    bi3[i] = l3 ? (l2 ? bi2[i] : eIdx) : bi3[i];
                    bv2[i] = l2 ? (l1 ? bv1[i] : d) : bv2[i];
                    bi2[i] = l2 ? (l1 ? bi1[i] : eIdx) : bi2[i];
                    bv1[i] = l1 ? (l0 ? bv0[i] : d) : bv1[i];
                    bi1[i] = l1 ? (l0 ? bi0[i] : eIdx) : bi1[i];
                    bv0[i] = l0 ? d : bv0[i];
                    bi0[i] = l0 ? eIdx : bi0[i];
                }
            }
        }
        __syncthreads();
    }

    float* out_q = out;
    float* out_i = out + (size_t)M * ZD;
    float* out_l = out_i + M;

    #pragma unroll 1
    for (int i = 0; i < 4; ++i) {
        const long r = rbase + g * 4 + i;

        float gmin = bv0[i];
        #pragma unroll
        for (int o = 1; o < 16; o <<= 1) gmin = fminf(gmin, __shfl_xor(gmin, o, 64));
        const float thr = gmin + taur[i];

        unsigned b0 = (unsigned)(__ballot(bv0[i] <= thr) >> (g * 16)) & 0xFFFFu;
        unsigned b1 = (unsigned)(__ballot(bv1[i] <= thr) >> (g * 16)) & 0xFFFFu;
        unsigned b2 = (unsigned)(__ballot(bv2[i] <= thr) >> (g * 16)) & 0xFFFFu;
        unsigned b3 = (unsigned)(__ballot(bv3[i] <= thr) >> (g * 16)) & 0xFFFFu;
        const int cnt = __popc(b0) + __popc(b1) + __popc(b2) + __popc(b3);
        const bool ex = (b3 != 0u) || (cnt > 7);

        if (cnt == 1 && !ex) {
            // single in-window candidate: provably the argmin; resolve now.
            if (bv0[i] <= thr) out_l[r] = (float)bi0[i];
        } else if (!ex) {
            float* rec = out_q + (size_t)r * ZD;
            if (lg == 0) {
                rec[0] = (float)cnt;
                out_l[r] = -(float)cnt;          // verify marker
            }
            const unsigned mlt = (1u << lg) - 1u;
            int base = 1;
            if (bv0[i] <= thr) rec[base + __popc(b0 & mlt)] = (float)bi0[i];
            base += __popc(b0);
            if (bv1[i] <= thr) rec[base + __popc(b1 & mlt)] = (float)bi1[i];
            base += __popc(b1);
            if (bv2[i] <= thr) rec[base + __popc(b2 & mlt)] = (float)bi2[i];
        } else {
            if (lg == 0) out_l[r] = -99.0f;      // exhaustive marker
        }
    }
}

// ---------------------------------------------------------------------------
// K2 merged finalize+stream: 8192 blocks x 256 thr, 16 rows/block (4/wave).
// Per wave: read markers; for each row needing verification, run R10's
// proven verify body (coalesced 1KB stages of h + candidate e rows into the
// wave's LDS slice, one bit-exact chain per lane, lex (d,idx) reduce) — the
// latency hides under the other 32K waves' pure-BW epilogue traffic.
// Then R1's byte-exact epilogue for all 4 rows.
// ---------------------------------------------------------------------------
__global__ __launch_bounds__(256) void vq_fs(const float* __restrict__ h,
                                             const float* __restrict__ emb,
                                             const float* __restrict__ en,
                                             float* __restrict__ out, int M) {
    extern __shared__ float Lall[];          // 4 waves x 8 rows x 260 floats
    const int t    = threadIdx.x;
    const int wv   = t >> 6;      // 0..3
    const int lane = t & 63;
    const int g    = lane >> 4;   // 0..3
    const int lg   = lane & 15;
    float* Lw = Lall + wv * (8 * 260);

    float* out_q = out;
    float* out_i = out + (size_t)M * ZD;
    float* out_l = out_i + M;
    const float INF = __builtin_inff();

    const long r = (long)blockIdx.x * 16 + wv * 4 + g;   // this group's row
    const float mk = out_l[r];                            // marker/besti
    int besti = (mk >= 0.f) ? (int)mk : 0;

    // ---- wave-level: resolve rows needing verification, one at a time ----
    unsigned long long vb = __ballot(mk < 0.f);
    #pragma unroll 1
    for (int gx = 0; gx < 4; ++gx) {
        if (!((vb >> (gx * 16)) & 1ull)) continue;
        const long rx = (long)blockIdx.x * 16 + wv * 4 + gx;
        const float mx = __shfl(mk, gx * 16, 64);
        const float hnx = out_i[rx];

        asm volatile("s_waitcnt lgkmcnt(0)" ::: "memory");  // WAR vs prev row

        int bix;
        if (mx > -50.f) {
            const int cnt = -(int)mx;                       // 2..7
            const float* rec = out_q + (size_t)rx * ZD;
            const float4 rA = *(const float4*)(rec);        // cnt,i0,i1,i2
            const float4 rB = *(const float4*)(rec + 4);    // i3,i4,i5,i6

            { // stage h row (coalesced 1KB, whole wave)
                float4 v = *(const float4*)(h + (size_t)rx * ZD + lane * 4);
                *(float4*)(Lw + lane * 4) = v;
            }
            #pragma unroll 1
            for (int q = 0; q < cnt; ++q) {   // stage candidate e rows
                const float fq = (q == 0) ? rA.y : (q == 1) ? rA.z : (q == 2) ? rA.w
                               : (q == 3) ? rB.x : (q == 4) ? rB.y : (q == 5) ? rB.z : rB.w;
                const int eidx = (int)fq;
                float4 v = *(const float4*)(emb + (size_t)eidx * ZD + lane * 4);
                *(float4*)(Lw + (1 + q) * 260 + lane * 4) = v;
            }
            asm volatile("s_waitcnt lgkmcnt(0)" ::: "memory");  // RAW

            float bd = INF;
            int   bi = 0x7FFFFFFF;
            if (lane < cnt) {
                const float fq = (lane == 0) ? rA.y : (lane == 1) ? rA.z : (lane == 2) ? rA.w
                               : (lane == 3) ? rB.x : (lane == 4) ? rB.y : (lane == 5) ? rB.z : rB.w;
                const int idx = (int)fq;
                const float* hl = Lw;
                const float* el = Lw + (1 + lane) * 260;
                float dot = 0.f;
                #pragma unroll 8
                for (int k = 0; k < ZD; k += 4) {
                    dot = fmaf(hl[k],     el[k],     dot);
                    dot = fmaf(hl[k + 1], el[k + 1], dot);
                    dot = fmaf(hl[k + 2], el[k + 2], dot);
                    dot = fmaf(hl[k + 3], el[k + 3], dot);
                }
                bd = __fsub_rn(__fadd_rn(hnx, en[idx]), __fmul_rn(2.0f, dot));
                bi = idx;
            }
            #pragma unroll
            for (int o = 1; o < 8; o <<= 1) {  // lex (d,idx) min, lanes 0..7
                float ov = __shfl_xor(bd, o, 8);
                int   oi = __shfl_xor(bi, o, 8);
                if (ov < bd || (ov == bd && oi < bi)) { bd = ov; bi = oi; }
            }
            bix = __shfl(bi, 0, 64);
        } else {
            // exhaustive (ultra-rare): h from LDS, lane-parallel over entries
            {
                float4 v = *(const float4*)(h + (size_t)rx * ZD + lane * 4);
                *(float4*)(Lw + lane * 4) = v;
            }
            asm volatile("s_waitcnt lgkmcnt(0)" ::: "memory");
            float bd = INF;
            int   bi = 0x7FFFFFFF;
            for (int e = lane; e < NE; e += 64) {
                const float* er = emb + (size_t)e * ZD;
                float dot = 0.f;
                #pragma unroll 8
                for (int k = 0; k < ZD; k += 4) {
                    float4 ev = *(const float4*)(er + k);
                    dot = fmaf(Lw[k],     ev.x, dot);
                    dot = fmaf(Lw[k + 1], ev.y, dot);
                    dot = fmaf(Lw[k + 2], ev.z, dot);
                    dot = fmaf(Lw[k + 3], ev.w, dot);
                }
                float dx = __fsub_rn(__fadd_rn(hnx, en[e]), __fmul_rn(2.0f, dot));
                if (dx < bd || (dx == bd && e < bi)) { bd = dx; bi = e; }
            }
            #pragma unroll
            for (int o = 1; o < 64; o <<= 1) {
                float ov = __shfl_xor(bd, o, 64);
                int   oi = __shfl_xor(bi, o, 64);
                if (ov < bd || (ov == bd && oi < bi)) { bd = ov; bi = oi; }
            }
            bix = __shfl(bi, 0, 64);
        }
        if (g == gx) besti = bix;
    }

    // ---- stream: R1's byte-exact epilogue for this group's row ----
    const float* hrow = h + (size_t)r * ZD;
    const float* erow = emb + (size_t)besti * ZD;
    float csum = 0.0f;
    #pragma unroll
    for (int q4 = 0; q4 < 4; ++q4) {
        int k = lg * 16 + q4 * 4;
        float4 hv = *(const float4*)(hrow + k);
        float4 ev = *(const float4*)(erow + k);
        float dx = __fsub_rn(ev.x, hv.x);
        float dy = __fsub_rn(ev.y, hv.y);
        float dz = __fsub_rn(ev.z, hv.z);
        float dw = __fsub_rn(ev.w, hv.w);
        float4 o;
        o.x = __fadd_rn(hv.x, dx);
        o.y = __fadd_rn(hv.y, dy);
        o.z = __fadd_rn(hv.z, dz);
        o.w = __fadd_rn(hv.w, dw);
        *(float4*)(out_q + (size_t)r * ZD + k) = o;
        csum = fmaf(dx, dx, csum);
        csum = fmaf(dy, dy, csum);
        csum = fmaf(dz, dz, csum);
        csum = fmaf(dw, dw, csum);
    }
    #pragma unroll
    for (int o2 = 1; o2 < 16; o2 <<= 1) csum += __shfl_xor(csum, o2, 64);
    if (lg == 0) {
        float cmean = csum * (1.0f / 256.0f);
        out_i[r] = (float)besti;
        out_l[r] = __fadd_rn(__fmul_rn(cmean, 0.1f), __fmul_rn(cmean, 0.2f));
    }
}

extern "C" void kernel_launch(void* const* d_in, const int* in_sizes, int n_in,
                              void* d_out, int out_size, void* d_ws, size_t ws_size,
                              hipStream_t stream) {
    const float* h   = (const float*)d_in[0];
    const float* emb = (const float*)d_in[1];
    const int M = in_sizes[0] / ZD;   // 131072

    unsigned char* ebB = (unsigned char*)d_ws;               // 512 KB bf16 swizzled
    float* en = (float*)(ebB + (size_t)NP * ZD * 2);         // 4 KB

    float* out = (float*)d_out;
    unsigned short* hb = (unsigned short*)d_out;             // bf16 h in out_q region
    float* hn = out + (size_t)M * ZD;                        // hn in out_i region

    prep_e<<<NP / 64, 64, 0, stream>>>(emb, ebB, en);
    prep_h<<<M / 64, 256, 0, stream>>>(h, hb, hn);

    const size_t lds_bytes = 131072 + 1024;
    (void)hipFuncSetAttribute((const void*)vq_main,
                              hipFuncAttributeMaxDynamicSharedMemorySize,
                              (int)lds_bytes);
    vq_main<<<M / 256, 1024, lds_bytes, stream>>>(h, emb, ebB, en, out, M);

    const size_t fs_lds = 4 * 8 * 260 * sizeof(float);       // 33280 B
    vq_fs<<<M / 16, 256, fs_lds, stream>>>(h, emb, en, out, M);
}